// Round 3
// baseline (3343.372 us; speedup 1.0000x reference)
//
#include <hip/hip_runtime.h>

// Two-layer tanh RNN, H=32, B=64, T=16384. Latency-bound sequential scan.
//
// Round-19: fuse BOTH layers into one wave — two independent dependency
// chains per iteration hide each other's latency bubbles.
// R18 analysis: step = 286 cyc but issue is only ~100 cyc/wave; a solo
// chain on a solo SIMD pays every latency (exp2, rcp, DPP, readlane)
// as dead time. Fusion doubles per-wave issue but overlaps two chains.
//
// Four-matrix lane split, zero cross-half traffic:
//   dot-A (vs h0(i-1)): lo = Whh0 rows (h0 update, lo), hi = Wih1 rows
//                       (u = Wih1.h0 + b1, consumed in hi lanes).
//   dot-B (vs h1(i-2)): hi = Whh1 rows (h1 update, hi), lo = Wout dup
//                       (out(i-2), stored from lo lanes).
// h0 state lives in lo lanes, h1 state in hi lanes; h1n = tanh(accA+accB)
// entirely in hi lanes. No LDS, no barriers, no u-window: the layer-1
// step reads last iteration's registers. One shared tanh via mask-select.
// Iteration i: computes h0(i) (lo) and h1(i-1) (hi) and out(i-2) (lo).

#define T_LEN 16384
#define B_SZ  64
#define NW    (T_LEN / 32)   // 512 windows

#if __has_builtin(__builtin_amdgcn_exp2f)
#define EXP2(x) __builtin_amdgcn_exp2f(x)
#else
#define EXP2(x) exp2f(x)
#endif

typedef _Float16 h2 __attribute__((ext_vector_type(2)));

__device__ __forceinline__ float rl(float v, int lane) {
  return __int_as_float(__builtin_amdgcn_readlane(__float_as_int(v), lane));
}

__device__ __forceinline__ h2 rl_h2(h2 v, int lane) {
  int o = __builtin_amdgcn_readlane(__builtin_bit_cast(int, v), lane);
  return __builtin_bit_cast(h2, o);
}

__device__ __forceinline__ float tanh_fast(float v) {
  // tanh(v) = 1 - 2/(e^{2v}+1); e^{2v} = 2^{v*2*log2(e)}. 5-dep chain.
  float e = EXP2(v * 2.885390082f);
  return fmaf(-2.f, __builtin_amdgcn_rcpf(e + 1.f), 1.f);
}

#if __has_builtin(__builtin_amdgcn_fdot2)
#define FDOT2(a, b, c) __builtin_amdgcn_fdot2((a), (b), (c), false)
#else
#define FDOT2(a, b, c) \
  fmaf((float)(a).x, (float)(b).x, fmaf((float)(a).y, (float)(b).y, (c)))
#endif

// Pack this lane's state f16 with its pair-neighbor's f16 via one DPP:
// even lane 2j ends with (h[2j], h[2j+1]). Odd lanes: garbage, never read.
__device__ __forceinline__ h2 pack_state(float h) {
  _Float16 hf = (_Float16)h;                       // v_cvt_f16_f32
  int lo = (int)__builtin_bit_cast(unsigned short, hf);
  int sw = __builtin_amdgcn_update_dpp(0, lo, 0xB1, 0xF, 0xF, true);
  h2 p;
  p.x = hf;
  p.y = __builtin_bit_cast(_Float16, (unsigned short)(sw & 0xffff));
  return p;
}

// Broadcast 16 packed pairs from even lanes (base + 0,2,...,30).
#define BCASTH(dst, src_pk, base)                                 \
  _Pragma("unroll")                                               \
  for (int j_ = 0; j_ < 16; ++j_) (dst)[j_] = rl_h2((src_pk), (base) + 2 * j_);

// 32-term dot via 16 dot2, 4 accumulators (depth 4) + 2-level tree.
__device__ __forceinline__ float dot32h(const h2* w, const h2* hb, float seed) {
  float a0 = seed, a1 = 0.f, a2 = 0.f, a3 = 0.f;
#pragma unroll
  for (int j = 0; j < 4; ++j) {
    a0 = FDOT2(w[4 * j + 0], hb[4 * j + 0], a0);
    a1 = FDOT2(w[4 * j + 1], hb[4 * j + 1], a1);
    a2 = FDOT2(w[4 * j + 2], hb[4 * j + 2], a2);
    a3 = FDOT2(w[4 * j + 3], hb[4 * j + 3], a3);
  }
  return (a0 + a1) + (a2 + a3);
}

__global__ __launch_bounds__(64, 1) void rnn2_kernel(
    const float* __restrict__ x,    const float* __restrict__ hs,
    const float* __restrict__ Wih0, const float* __restrict__ Whh0,
    const float* __restrict__ bih0, const float* __restrict__ bhh0,
    const float* __restrict__ Wih1, const float* __restrict__ Whh1,
    const float* __restrict__ bih1, const float* __restrict__ bhh1,
    const float* __restrict__ Wout, const float* __restrict__ bout,
    float* __restrict__ out)
{
  const int  m   = (int)threadIdx.x;    // 0..63, one wave per block
  const int  r   = m & 31;              // row owned by this lane
  const bool hi  = (m >= 32);           // layer-1 half
  const int  b   = (int)blockIdx.x;

  // Per-lane rows (16 f16 pairs each):
  //  wA: lo = Whh0[r], hi = Wih1[r].   wB: lo = Wout (dup), hi = Whh1[r].
  const float* pwA = hi ? (Wih1 + r * 32) : (Whh0 + r * 32);
  const float* pwB = hi ? (Whh1 + r * 32) : Wout;
  h2 wA[16], wB[16];
#pragma unroll
  for (int k = 0; k < 8; ++k) {
    float4 qa = ((const float4*)pwA)[k];
    wA[2 * k].x     = (_Float16)qa.x;  wA[2 * k].y     = (_Float16)qa.y;
    wA[2 * k + 1].x = (_Float16)qa.z;  wA[2 * k + 1].y = (_Float16)qa.w;
    float4 qb = ((const float4*)pwB)[k];
    wB[2 * k].x     = (_Float16)qb.x;  wB[2 * k].y     = (_Float16)qb.y;
    wB[2 * k + 1].x = (_Float16)qb.z;  wB[2 * k + 1].y = (_Float16)qb.w;
  }

  // Seeds: lo lanes x(t)*Wih0[r] + (b_ih0+b_hh0)[r]; hi lanes (b_ih1+b_hh1)[r]
  // (xw=0 in hi lanes makes one shared fma correct for both halves).
  const float xw   = hi ? 0.f : Wih0[r];
  const float binv = hi ? (bih1[r] + bhh1[r]) : (bih0[r] + bhh0[r]);
  const float bo   = bout[0];

  // States: h0 lives in lo lanes (lane r holds h0[r]); h1 in hi lanes
  // (lane 32+r holds h1[r]). The opposite half's copy is garbage, never read.
  float h0cur = hs[b * 32 + r];
  float h1cur = hs[2048 + b * 32 + r];

  const float* xb   = x + (size_t)b * T_LEN;
  float*       outp = out + (size_t)b * T_LEN;       // outs[b*T + t]
  float*       hf   = out + (size_t)B_SZ * T_LEN;    // h_final [2,B,H]

  float obuf = 0.f;
  float xcur = xb[m];                   // window 0 chunk (lanes 0..31 used)

  for (int wdx = 0; wdx < NW; ++wdx) {
    // Prefetch next window's x chunk; consumed 32 iterations from now.
    float xnext = 0.f;
    if (wdx + 1 < NW) {
      int xi = 32 * (wdx + 1) + m; if (xi > T_LEN - 1) xi = T_LEN - 1;
      xnext = xb[xi];
    }
#pragma unroll 4
    for (int t2 = 0; t2 < 32; ++t2) {
      // Chain 0: h0(i-1) broadcast (even lo lanes).
      h2 hpk0 = pack_state(h0cur);
      h2 hb0[16];
      BCASTH(hb0, hpk0, 0);
      // Chain 1: h1(i-2) broadcast (even hi lanes).
      h2 hpk1 = pack_state(h1cur);
      h2 hb1[16];
      BCASTH(hb1, hpk1, 32);
      float xv   = rl(xcur, t2);                // x(i)  (off-chain)
      float seed = fmaf(xv, xw, binv);          // lo: x*w+b0; hi: b1
      float accA = dot32h(wA, hb0, seed);       // lo: pre-h0; hi: u(i-1)
      float accB = dot32h(wB, hb1, 0.f);        // lo: out(i-2)-bo; hi: Whh1 dot
      // Shared tanh: lo wants accA, hi wants accA+accB.
      float tin = accA + (hi ? accB : 0.f);
      float tv  = tanh_fast(tin);
      h0cur = tv;                               // hi-lane copy garbage, unread
      obuf  = (m == t2) ? accB : obuf;          // lo lane t2: out(i-2)-bo
      if (wdx + t2 != 0) h1cur = tv;            // skip only i==0 (h1(-1)=hs1)
    }
    // Coalesced per-window store: lane k holds out(32*wdx + k - 2).
    const int idx = 32 * wdx - 2 + m;
    if (!hi && idx >= 0) outp[idx] = obuf + bo;
    xcur = xnext;
  }

  // Epilogue "iteration T": h1(T-1), out(T-2); then out(T-1); h_finals.
  {
    h2 hpk0 = pack_state(h0cur);                // h0(T-1)
    h2 hb0[16];
    BCASTH(hb0, hpk0, 0);
    h2 hpk1 = pack_state(h1cur);                // h1(T-2)
    h2 hb1[16];
    BCASTH(hb1, hpk1, 32);
    float accA = dot32h(wA, hb0, binv);         // hi: u(T-1) (lo unused)
    float accB = dot32h(wB, hb1, 0.f);          // lo: out(T-2)-bo; hi: Whh1 dot
    if (m == 0) outp[T_LEN - 2] = accB + bo;
    float h1T = tanh_fast(accA + accB);         // valid in hi lanes
    h1cur = h1T;

    h2 hpk2 = pack_state(h1cur);                // h1(T-1) (hi lanes)
    h2 hb2[16];
    BCASTH(hb2, hpk2, 32);
    float accB2 = dot32h(wB, hb2, 0.f);         // lo: out(T-1)-bo
    if (m == 0) outp[T_LEN - 1] = accB2 + bo;

    if (!hi) hf[b * 32 + r] = h0cur;            // h_final layer 0 (lo lanes)
    else     hf[2048 + b * 32 + r] = h1cur;     // h_final layer 1 (hi lanes)
  }
}

extern "C" void kernel_launch(void* const* d_in, const int* in_sizes, int n_in,
                              void* d_out, int out_size, void* d_ws, size_t ws_size,
                              hipStream_t stream) {
  rnn2_kernel<<<dim3(B_SZ), dim3(64), 0, stream>>>(
      (const float*)d_in[0],  (const float*)d_in[1],  (const float*)d_in[2],
      (const float*)d_in[3],  (const float*)d_in[4],  (const float*)d_in[5],
      (const float*)d_in[6],  (const float*)d_in[7],  (const float*)d_in[8],
      (const float*)d_in[9],  (const float*)d_in[10], (const float*)d_in[11],
      (float*)d_out);
}

// Round 5
// 3340.575 us; speedup vs baseline: 1.0008x; 1.0008x over previous
//
#include <hip/hip_runtime.h>

// Two-layer tanh RNN, H=32, B=64, T=16384. Latency-bound sequential scan.
//
// Round-21 = Round-20 resubmission (previous bench died with "MI355X
// container failed twice" — infra error, no compile/correctness signal;
// lag structure re-audited and sound).
//
// Correct braid of both layers in ONE wave (R19 post-mortem: R19 joined
// the chains via a shared tanh and shared state register; this version
// keeps them fully separate so each chain's latency bubbles are filled by
// the other chain's instructions).
//  - chain-0 (h0): pack0 -> bcast0 -> dotA -> treeA -> tanh0. lo=Whh0 rows,
//    hi=Wih1 rows (u = b1 + Wih1.h0 rides the same 16 dot2).
//  - chain-1 (h1): pack1 -> bcast1 -> dotB(seed=u) -> tanh1. hi=Whh1 rows,
//    lo=Wout (dup) -> out rides the same 16 dot2.
//  - u handoff: register lag-1 (ureg = treeA-hi of previous step seeds
//    dotB). Branches off chain-0 BEFORE tanh0 -> non-binding.
//  - Lags: step i computes h0(i) [lo], h1(i-2) [hi], out(i-3) [lo].
//    Guards: h1 update skipped for i<2; out store skipped for idx<0.
//  - No LDS, no barriers, no second wave, no u-window.

#define T_LEN 16384
#define B_SZ  64
#define NW    (T_LEN / 32)   // 512 windows

#if __has_builtin(__builtin_amdgcn_exp2f)
#define EXP2(x) __builtin_amdgcn_exp2f(x)
#else
#define EXP2(x) exp2f(x)
#endif

typedef _Float16 h2 __attribute__((ext_vector_type(2)));

__device__ __forceinline__ float rl(float v, int lane) {
  return __int_as_float(__builtin_amdgcn_readlane(__float_as_int(v), lane));
}

__device__ __forceinline__ h2 rl_h2(h2 v, int lane) {
  int o = __builtin_amdgcn_readlane(__builtin_bit_cast(int, v), lane);
  return __builtin_bit_cast(h2, o);
}

__device__ __forceinline__ float tanh_fast(float v) {
  // tanh(v) = 1 - 2/(e^{2v}+1); e^{2v} = 2^{v*2*log2(e)}. 5-dep chain.
  float e = EXP2(v * 2.885390082f);
  return fmaf(-2.f, __builtin_amdgcn_rcpf(e + 1.f), 1.f);
}

#if __has_builtin(__builtin_amdgcn_fdot2)
#define FDOT2(a, b, c) __builtin_amdgcn_fdot2((a), (b), (c), false)
#else
#define FDOT2(a, b, c) \
  fmaf((float)(a).x, (float)(b).x, fmaf((float)(a).y, (float)(b).y, (c)))
#endif

// Pack this lane's state f16 with its pair-neighbor's f16 via one DPP:
// even lane 2j ends with (h[2j], h[2j+1]). Odd lanes: garbage, never read.
__device__ __forceinline__ h2 pack_state(float h) {
  _Float16 hf = (_Float16)h;                       // v_cvt_f16_f32
  int lo = (int)__builtin_bit_cast(unsigned short, hf);
  int sw = __builtin_amdgcn_update_dpp(0, lo, 0xB1, 0xF, 0xF, true);
  h2 p;
  p.x = hf;
  p.y = __builtin_bit_cast(_Float16, (unsigned short)(sw & 0xffff));
  return p;
}

// Broadcast 16 packed pairs from even lanes (base + 0,2,...,30).
#define BCASTH(dst, src_pk, base)                                 \
  _Pragma("unroll")                                               \
  for (int j_ = 0; j_ < 16; ++j_) (dst)[j_] = rl_h2((src_pk), (base) + 2 * j_);

// 32-term dot via 16 dot2, 4 accumulators (depth 4) + 2-level tree.
__device__ __forceinline__ float dot32h(const h2* w, const h2* hb, float seed) {
  float a0 = seed, a1 = 0.f, a2 = 0.f, a3 = 0.f;
#pragma unroll
  for (int j = 0; j < 4; ++j) {
    a0 = FDOT2(w[4 * j + 0], hb[4 * j + 0], a0);
    a1 = FDOT2(w[4 * j + 1], hb[4 * j + 1], a1);
    a2 = FDOT2(w[4 * j + 2], hb[4 * j + 2], a2);
    a3 = FDOT2(w[4 * j + 3], hb[4 * j + 3], a3);
  }
  return (a0 + a1) + (a2 + a3);
}

__global__ __launch_bounds__(64, 1) void rnn2_kernel(
    const float* __restrict__ x,    const float* __restrict__ hs,
    const float* __restrict__ Wih0, const float* __restrict__ Whh0,
    const float* __restrict__ bih0, const float* __restrict__ bhh0,
    const float* __restrict__ Wih1, const float* __restrict__ Whh1,
    const float* __restrict__ bih1, const float* __restrict__ bhh1,
    const float* __restrict__ Wout, const float* __restrict__ bout,
    float* __restrict__ out)
{
  const int  m   = (int)threadIdx.x;    // 0..63, one wave per block
  const int  r   = m & 31;              // row owned by this lane
  const bool hi  = (m >= 32);
  const int  b   = (int)blockIdx.x;

  // Per-lane rows (16 f16 pairs each):
  //  wA: lo = Whh0[r], hi = Wih1[r].   wB: lo = Wout (dup), hi = Whh1[r].
  const float* pwA = hi ? (Wih1 + r * 32) : (Whh0 + r * 32);
  const float* pwB = hi ? (Whh1 + r * 32) : Wout;
  h2 wA[16], wB[16];
#pragma unroll
  for (int k = 0; k < 8; ++k) {
    float4 qa = ((const float4*)pwA)[k];
    wA[2 * k].x     = (_Float16)qa.x;  wA[2 * k].y     = (_Float16)qa.y;
    wA[2 * k + 1].x = (_Float16)qa.z;  wA[2 * k + 1].y = (_Float16)qa.w;
    float4 qb = ((const float4*)pwB)[k];
    wB[2 * k].x     = (_Float16)qb.x;  wB[2 * k].y     = (_Float16)qb.y;
    wB[2 * k + 1].x = (_Float16)qb.z;  wB[2 * k + 1].y = (_Float16)qb.w;
  }

  // Seeds for dotA: lo lanes x(i)*Wih0[r] + (b_ih0+b_hh0)[r];
  // hi lanes (b_ih1+b_hh1)[r] (xw=0 there -> one shared fma).
  const float xw   = hi ? 0.f : Wih0[r];
  const float binv = hi ? (bih1[r] + bhh1[r]) : (bih0[r] + bhh0[r]);
  const float bo   = bout[0];

  // States: h0 in lo lanes (lane r holds h0[r]); h1 in hi lanes (lane 32+r
  // holds h1[r]). Opposite-half copies are garbage and never read.
  float h0cur = hs[b * 32 + r];          // h0(-1)
  float h1cur = hs[2048 + b * 32 + r];   // h1(-1)
  float ureg  = 0.f;                     // u(i-2) at entry to step i (hi)

  const float* xb   = x + (size_t)b * T_LEN;
  float*       outp = out + (size_t)b * T_LEN;       // outs[b*T + t]
  float*       hf   = out + (size_t)B_SZ * T_LEN;    // h_final [2,B,H]

  float obuf = 0.f;
  float xcur = xb[m];                   // window 0 chunk (lanes 0..31 used)

  for (int wdx = 0; wdx < NW; ++wdx) {
    // Prefetch next window's x chunk; consumed 32 iterations from now.
    float xnext = 0.f;
    if (wdx + 1 < NW) {
      int xi = 32 * (wdx + 1) + m; if (xi > T_LEN - 1) xi = T_LEN - 1;
      xnext = xb[xi];
    }
#pragma unroll 4
    for (int t2 = 0; t2 < 32; ++t2) {
      // --- chain-0 head: h0(i-1) broadcast (even lo lanes) ---
      h2 hpk0 = pack_state(h0cur);
      h2 hb0[16];
      BCASTH(hb0, hpk0, 0);
      // --- chain-1 head: h1(i-3) broadcast (even hi lanes) ---
      h2 hpk1 = pack_state(h1cur);
      h2 hb1[16];
      BCASTH(hb1, hpk1, 32);
      // Off-chain seeds.
      float xv    = rl(xcur, t2);               // x(i)
      float seedA = fmaf(xv, xw, binv);         // lo: x*w+b0; hi: b1
      float seedB = hi ? ureg : 0.f;            // hi: u(i-2); lo: 0
      // --- dots (each serves two matrices via the lane split) ---
      float accA = dot32h(wA, hb0, seedA);      // lo: pre-h0(i); hi: u(i-1)
      float accB = dot32h(wB, hb1, seedB);      // lo: out(i-3)-bo;
                                                // hi: u(i-2)+Whh1.h1(i-3)
      // --- chain-0 tail (independent of accB) ---
      float t0 = tanh_fast(accA);
      h0cur = t0;                               // valid lo; hi garbage unread
      ureg  = accA;                             // hi lanes: u(i-1) for i+1
      // --- chain-1 tail (independent of accA this step) ---
      float t1 = tanh_fast(accB);               // valid hi = h1(i-2)
      obuf = (m == t2) ? accB : obuf;           // lo lane t2: out(i-3)-bo
      if (32 * wdx + t2 >= 2) h1cur = t1;       // skip i=0,1 (h1 starts i=2)
    }
    // Coalesced per-window store: lane k holds out(32*wdx + k - 3).
    const int idx = 32 * wdx - 3 + m;
    if (!hi && idx >= 0) outp[idx] = obuf + bo;
    xcur = xnext;
  }

  // Epilogue. State: h0cur=h0(T-1), h1cur=h1(T-3), ureg(hi)=u(T-2).
  {
    // u(T-1) = b1 + Wih1.h0(T-1)  (hi lanes of a dotA pass).
    h2 hpk0 = pack_state(h0cur);
    h2 hb0[16];
    BCASTH(hb0, hpk0, 0);
    float uT1 = dot32h(wA, hb0, binv);          // hi: u(T-1)

    // E1: h1(T-2) = tanh(u(T-2) + Whh1.h1(T-3)); out(T-3).
    h2 hpk1 = pack_state(h1cur);
    h2 hb1[16];
    BCASTH(hb1, hpk1, 32);
    float acc1 = dot32h(wB, hb1, hi ? ureg : 0.f);
    if (m == 0) outp[T_LEN - 3] = acc1 + bo;    // lo: Wout.h1(T-3)
    h1cur = tanh_fast(acc1);                    // hi: h1(T-2)

    // E2: h1(T-1) = tanh(u(T-1) + Whh1.h1(T-2)); out(T-2).
    h2 hpk2 = pack_state(h1cur);
    h2 hb2[16];
    BCASTH(hb2, hpk2, 32);
    float acc2 = dot32h(wB, hb2, hi ? uT1 : 0.f);
    if (m == 0) outp[T_LEN - 2] = acc2 + bo;    // lo: Wout.h1(T-2)
    h1cur = tanh_fast(acc2);                    // hi: h1(T-1)

    // E3: out(T-1) = Wout.h1(T-1) + bo.
    h2 hpk3 = pack_state(h1cur);
    h2 hb3[16];
    BCASTH(hb3, hpk3, 32);
    float acc3 = dot32h(wB, hb3, 0.f);
    if (m == 0) outp[T_LEN - 1] = acc3 + bo;

    if (!hi) hf[b * 32 + r] = h0cur;            // h_final layer 0
    else     hf[2048 + b * 32 + r] = h1cur;     // h_final layer 1
  }
}

extern "C" void kernel_launch(void* const* d_in, const int* in_sizes, int n_in,
                              void* d_out, int out_size, void* d_ws, size_t ws_size,
                              hipStream_t stream) {
  rnn2_kernel<<<dim3(B_SZ), dim3(64), 0, stream>>>(
      (const float*)d_in[0],  (const float*)d_in[1],  (const float*)d_in[2],
      (const float*)d_in[3],  (const float*)d_in[4],  (const float*)d_in[5],
      (const float*)d_in[6],  (const float*)d_in[7],  (const float*)d_in[8],
      (const float*)d_in[9],  (const float*)d_in[10], (const float*)d_in[11],
      (float*)d_out);
}

// Round 6
// 3287.847 us; speedup vs baseline: 1.0169x; 1.0160x over previous
//
#include <hip/hip_runtime.h>

// Two-layer tanh RNN, H=32, B=64, T=16384. Latency-bound sequential scan.
//
// Round-22: R18 inner code (proven, 1952 us) + SIMD-level multithreading.
// R19/R21 post-mortem: braiding two chains in ONE wave never overlaps on
// an in-order SIMD (3340 us ~= 2x solo chain) — overlap must come from the
// HW wave scheduler, which needs >=2 independent waves PER SIMD. Batch dim
// supplies independent chains: merge 4 batch elements per block ->
// 512 threads = 8 waves = 2 waves/SIMD, all inner code identical to R18.
//  - wave layout: tid = g*128 + wv*64 + m; g = batch-in-block (0..3),
//    wv = 0 (layer-0 wave A) / 1 (layer-1 wave B), m = lane.
//  - per-g u-window ring in LDS (4 x 2 x 1024 floats = 32 KB) + shared
//    write sink (4 KB, never read).
//  - one __syncthreads per 32-step window, all 4 pairs in lockstep.

#define T_LEN 16384
#define B_SZ  64
#define BPB   4              // batch elements per block
#define NW    (T_LEN / 32)   // 512 windows

#if __has_builtin(__builtin_amdgcn_exp2f)
#define EXP2(x) __builtin_amdgcn_exp2f(x)
#else
#define EXP2(x) exp2f(x)
#endif

typedef _Float16 h2 __attribute__((ext_vector_type(2)));

__device__ __forceinline__ float rl(float v, int lane) {
  return __int_as_float(__builtin_amdgcn_readlane(__float_as_int(v), lane));
}

__device__ __forceinline__ h2 rl_h2(h2 v, int lane) {
  int o = __builtin_amdgcn_readlane(__builtin_bit_cast(int, v), lane);
  return __builtin_bit_cast(h2, o);
}

// quad_perm([1,0,3,2]): each lane sees its pair-neighbor's value.
__device__ __forceinline__ float pair_swap(float v) {
  int t = __builtin_amdgcn_update_dpp(0, __float_as_int(v), 0xB1, 0xF, 0xF, true);
  return __int_as_float(t);
}

__device__ __forceinline__ float tanh_fast(float v) {
  // tanh(v) = 1 - 2/(e^{2v}+1); e^{2v} = 2^{v*2*log2(e)}. 5-dep chain.
  float e = EXP2(v * 2.885390082f);
  return fmaf(-2.f, __builtin_amdgcn_rcpf(e + 1.f), 1.f);
}

#if __has_builtin(__builtin_amdgcn_fdot2)
#define FDOT2(a, b, c) __builtin_amdgcn_fdot2((a), (b), (c), false)
#else
#define FDOT2(a, b, c) \
  fmaf((float)(a).x, (float)(b).x, fmaf((float)(a).y, (float)(b).y, (c)))
#endif

// Pack this lane's state with its pair-neighbor: even lane 2j ends up with
// (h[2j], h[2j+1]). Odd/hi lanes hold swapped/garbage pairs — never read.
__device__ __forceinline__ h2 pack_state(float hcur) {
  float hsw = pair_swap(hcur);
  h2 p;
  p.x = (_Float16)hcur;
  p.y = (_Float16)hsw;
  return p;
}

// Broadcast 16 packed pairs from even lanes 0,2,...,30 into uniform regs.
#define BCASTH(dst, src_pk)                                  \
  _Pragma("unroll")                                          \
  for (int j_ = 0; j_ < 16; ++j_) (dst)[j_] = rl_h2((src_pk), 2 * j_);

// 32-term dot via 16 dot2, 4 accumulators (depth 4) + 2-level tree.
__device__ __forceinline__ float dot32h(const h2* w, const h2* hb, float seed) {
  float a0 = seed, a1 = 0.f, a2 = 0.f, a3 = 0.f;
#pragma unroll
  for (int j = 0; j < 4; ++j) {
    a0 = FDOT2(w[4 * j + 0], hb[4 * j + 0], a0);
    a1 = FDOT2(w[4 * j + 1], hb[4 * j + 1], a1);
    a2 = FDOT2(w[4 * j + 2], hb[4 * j + 2], a2);
    a3 = FDOT2(w[4 * j + 3], hb[4 * j + 3], a3);
  }
  return (a0 + a1) + (a2 + a3);
}

__global__ __launch_bounds__(512, 1) void rnn2_kernel(
    const float* __restrict__ x,    const float* __restrict__ hs,
    const float* __restrict__ Wih0, const float* __restrict__ Whh0,
    const float* __restrict__ bih0, const float* __restrict__ bhh0,
    const float* __restrict__ Wih1, const float* __restrict__ Whh1,
    const float* __restrict__ bih1, const float* __restrict__ bhh1,
    const float* __restrict__ Wout, const float* __restrict__ bout,
    float* __restrict__ out)
{
  __shared__ __align__(16) float uwin[BPB][2][1024]; // A->B; slot t2*32 + row
  __shared__ __align__(16) float scratch[1024];      // write sink (never read)

  const int  tid = (int)threadIdx.x;
  const int  g   = tid >> 7;            // batch-in-block 0..3
  const int  loc = tid & 127;
  const int  wv  = loc >> 6;            // 0 = wave A (h0), 1 = wave B (h1)
  const int  m   = loc & 63;
  const int  r   = m & 31;              // row owned by this lane
  const bool hi  = (m >= 32);           // secondary-matrix half
  const int  b   = (int)blockIdx.x * BPB + g;

  // Per-lane full 32-float row, packed to 16 f16 pairs:
  //  A: lo = Whh0[r], hi = Wih1[r].  B: lo = Whh1[r], hi = Wout (row 0, dup).
  const float* pw = (wv == 0) ? (hi ? (Wih1 + r * 32) : (Whh0 + r * 32))
                              : (hi ? Wout : (Whh1 + r * 32));
  h2 w[16];
#pragma unroll
  for (int k = 0; k < 8; ++k) {
    float4 q = ((const float4*)pw)[k];
    w[2 * k].x     = (_Float16)q.x;
    w[2 * k].y     = (_Float16)q.y;
    w[2 * k + 1].x = (_Float16)q.z;
    w[2 * k + 1].y = (_Float16)q.w;
  }

  float xw = 0.f, binv = 0.f;
  if (wv == 0) {
    if (hi) binv = bih1[r] + bhh1[r];            // u seed: b1 (no x term)
    else  { binv = bih0[r] + bhh0[r]; xw = Wih0[r]; }
  }
  const float bo = bout[0];

  // State register: lane k (k<32) holds h[k] in f32. Hi lanes carry garbage
  // copies; pack_state/BCASTH only read lanes 0..31 (even lanes).
  float hcur = (wv == 0) ? hs[b * 32 + r] : hs[2048 + b * 32 + r];

  // Wave A publish pointers: hi lanes -> uwin row r, lo lanes -> scratch.
  float* up0 = hi ? &uwin[g][0][r] : &scratch[r];
  float* up1 = hi ? &uwin[g][1][r] : &scratch[r];

  const float* xb   = x + (size_t)b * T_LEN;
  float*       outp = out + (size_t)b * T_LEN;       // outs[b*T + t]
  float*       hf   = out + (size_t)B_SZ * T_LEN;    // h_final [2,B,H]

  float obuf = 0.f;
  float xcur = 0.f;
  if (wv == 0) xcur = xb[m];            // window 0 chunk (lanes 0..31 used)

  for (int wdx = 0; wdx <= NW; ++wdx) {
    if (wv == 0) {
      if (wdx < NW) {
        // Prefetch next window's x chunk; consumed 32 steps from now.
        float xnext = 0.f;
        if (wdx + 1 < NW) {
          int xi = 32 * (wdx + 1) + m; if (xi > T_LEN - 1) xi = T_LEN - 1;
          xnext = xb[xi];
        }
        float* up = (wdx & 1) ? up1 : up0;
#pragma unroll 4
        for (int t2 = 0; t2 < 32; ++t2) {
          h2 hpk = pack_state(hcur);        // h0n(t-1) packed pairs
          h2 hb[16];
          BCASTH(hb, hpk);
          float xv   = rl(xcur, t2);        // x(t)   (off-chain)
          float seed = fmaf(xv, xw, binv);  // lo: x*Wih0 + b0; hi: b1
          float acc  = dot32h(w, hb, seed); // lo: tanh arg; hi: u(t-1)
          up[t2 * 32] = acc;                // hi publishes u; lo -> scratch
          hcur = tanh_fast(acc);            // lo lanes: h0n(t)
        }
        xcur = xnext;
      }
    } else {
      if (wdx >= 1) {
        const int wb = wdx - 1;             // steps t = 32*wb-1 .. 32*wb+30
        const float* ub = &uwin[g][wb & 1][r];
        float uval = ub[0];                 // u(32*wb-1); all lanes broadcast
#pragma unroll 4
        for (int t2 = 0; t2 < 32; ++t2) {
          const int t = 32 * wb - 1 + t2;
          h2 hpk = pack_state(hcur);        // h1n(t-1) packed pairs
          h2 hb[16];
          BCASTH(hb, hpk);
          float acc = dot32h(w, hb, 0.f);   // lo: Whh1 dot; hi: Wout dot
          float unext = ub[((t2 + 1) & 31) * 32];  // pipelined u-read
          float h1n = tanh_fast(uval + acc);
          obuf = (m == 32 + t2) ? acc : obuf;      // hi lane t2: out(t-1)-bo
          if (t >= 0) hcur = h1n;           // uniform guard (skips wb=0,t2=0)
          uval = unext;
        }
        const int idx = 32 * wb - 2 + r;    // hi lane 32+k holds out(32wb-2+k)
        if (hi && idx >= 0) outp[idx] = obuf + bo;   // coalesced store
      }
    }
    __syncthreads();   // window handoff (uwin parity swap)
  }

  // Epilogue 1 (wave A): publish u(T-1) from h0n(T-1); store h_final L0.
  if (wv == 0) {
    h2 hpk = pack_state(hcur);              // h0n(T-1)
    h2 hb[16];
    BCASTH(hb, hpk);
    float acc = dot32h(w, hb, binv);        // hi: b1 + Wih1 . h0n(T-1)
    if (hi) uwin[g][0][r] = acc;
    else    hf[b * 32 + r] = hcur;          // h_final layer 0 (full f32)
  }
  __syncthreads();

  // Epilogue 2 (wave B): h1n(T-1), out(T-2), out(T-1), h_final L1.
  if (wv == 1) {
    float uT = uwin[g][0][r];
    h2 hpk = pack_state(hcur);              // h1n(T-2)
    h2 hb[16];
    BCASTH(hb, hpk);
    float acc = dot32h(w, hb, 0.f);
    if (m == 32) outp[T_LEN - 2] = acc + bo;      // Wout . h1n(T-2)
    float h1T = tanh_fast(uT + acc);
    h2 hpk2 = pack_state(h1T);              // h1n(T-1)
    h2 hb2[16];
    BCASTH(hb2, hpk2);
    float acc2 = dot32h(w, hb2, 0.f);
    if (m == 32) outp[T_LEN - 1] = acc2 + bo;     // Wout . h1n(T-1)
    if (!hi) hf[2048 + b * 32 + r] = h1T;   // h_final layer 1 (full f32)
  }
}

extern "C" void kernel_launch(void* const* d_in, const int* in_sizes, int n_in,
                              void* d_out, int out_size, void* d_ws, size_t ws_size,
                              hipStream_t stream) {
  rnn2_kernel<<<dim3(B_SZ / BPB), dim3(512), 0, stream>>>(
      (const float*)d_in[0],  (const float*)d_in[1],  (const float*)d_in[2],
      (const float*)d_in[3],  (const float*)d_in[4],  (const float*)d_in[5],
      (const float*)d_in[6],  (const float*)d_in[7],  (const float*)d_in[8],
      (const float*)d_in[9],  (const float*)d_in[10], (const float*)d_in[11],
      (float*)d_out);
}

// Round 9
// 2114.055 us; speedup vs baseline: 1.5815x; 1.5552x over previous
//
#include <hip/hip_runtime.h>

// Two-layer tanh RNN, H=32, B=64, T=16384. Latency-bound sequential scan.
//
// Round-25: revert to proven R18 (1952 us) + sched_barrier broadcast/dot
// split. R23/R24 (hand-scheduled asm) failed with BIT-IDENTICAL absmax with
// and without wait-state padding -> deterministic asm bug, unobservable
// without disasm; asm path abandoned.
// Theory retained: R18's 286 cyc/step = issue(~100) + serial tail(~55) +
// ~130 cyc of per-pair v_readlane->v_dot2 SGPR-latency stalls (compiler
// interleaves rl:dot 1:1). Fix at C level, zero semantic risk:
// __builtin_amdgcn_sched_barrier(0) between BCASTH and dot32h forces all
// 16 readlanes to issue BEFORE any dot — first dot pays one readlane
// latency, the other 15 hide under issue.
// All arithmetic bit-identical to R18 => absmax must be exactly 0.001953125.

#define T_LEN 16384
#define B_SZ  64
#define NW    (T_LEN / 32)   // 512 windows

#if __has_builtin(__builtin_amdgcn_exp2f)
#define EXP2(x) __builtin_amdgcn_exp2f(x)
#else
#define EXP2(x) exp2f(x)
#endif

#if __has_builtin(__builtin_amdgcn_sched_barrier)
#define SCHED_FENCE() __builtin_amdgcn_sched_barrier(0)
#else
#define SCHED_FENCE()
#endif

typedef _Float16 h2 __attribute__((ext_vector_type(2)));

__device__ __forceinline__ float rl(float v, int lane) {
  return __int_as_float(__builtin_amdgcn_readlane(__float_as_int(v), lane));
}

__device__ __forceinline__ h2 rl_h2(h2 v, int lane) {
  int o = __builtin_amdgcn_readlane(__builtin_bit_cast(int, v), lane);
  return __builtin_bit_cast(h2, o);
}

// quad_perm([1,0,3,2]): each lane sees its pair-neighbor's value.
__device__ __forceinline__ float pair_swap(float v) {
  int t = __builtin_amdgcn_update_dpp(0, __float_as_int(v), 0xB1, 0xF, 0xF, true);
  return __int_as_float(t);
}

__device__ __forceinline__ float tanh_fast(float v) {
  // tanh(v) = 1 - 2/(e^{2v}+1); e^{2v} = 2^{v*2*log2(e)}. 5-dep chain.
  float e = EXP2(v * 2.885390082f);
  return fmaf(-2.f, __builtin_amdgcn_rcpf(e + 1.f), 1.f);
}

#if __has_builtin(__builtin_amdgcn_fdot2)
#define FDOT2(a, b, c) __builtin_amdgcn_fdot2((a), (b), (c), false)
#else
#define FDOT2(a, b, c) \
  fmaf((float)(a).x, (float)(b).x, fmaf((float)(a).y, (float)(b).y, (c)))
#endif

// Pack this lane's state with its pair-neighbor: even lane 2j ends up with
// (h[2j], h[2j+1]). Odd/hi lanes hold swapped/garbage pairs — never read.
__device__ __forceinline__ h2 pack_state(float hcur) {
  float hsw = pair_swap(hcur);
  h2 p;
  p.x = (_Float16)hcur;
  p.y = (_Float16)hsw;
  return p;
}

// Broadcast 16 packed pairs from even lanes 0,2,...,30 into uniform regs.
#define BCASTH(dst, src_pk)                                  \
  _Pragma("unroll")                                          \
  for (int j_ = 0; j_ < 16; ++j_) (dst)[j_] = rl_h2((src_pk), 2 * j_);

// 32-term dot via 16 dot2, 4 accumulators (depth 4) + 2-level tree.
__device__ __forceinline__ float dot32h(const h2* w, const h2* hb, float seed) {
  float a0 = seed, a1 = 0.f, a2 = 0.f, a3 = 0.f;
#pragma unroll
  for (int j = 0; j < 4; ++j) {
    a0 = FDOT2(w[4 * j + 0], hb[4 * j + 0], a0);
    a1 = FDOT2(w[4 * j + 1], hb[4 * j + 1], a1);
    a2 = FDOT2(w[4 * j + 2], hb[4 * j + 2], a2);
    a3 = FDOT2(w[4 * j + 3], hb[4 * j + 3], a3);
  }
  return (a0 + a1) + (a2 + a3);
}

__global__ __launch_bounds__(128, 1) void rnn2_kernel(
    const float* __restrict__ x,    const float* __restrict__ hs,
    const float* __restrict__ Wih0, const float* __restrict__ Whh0,
    const float* __restrict__ bih0, const float* __restrict__ bhh0,
    const float* __restrict__ Wih1, const float* __restrict__ Whh1,
    const float* __restrict__ bih1, const float* __restrict__ bhh1,
    const float* __restrict__ Wout, const float* __restrict__ bout,
    float* __restrict__ out)
{
  __shared__ __align__(16) float uwin[2][1024];   // A->B; slot t2*32 + row
  __shared__ __align__(16) float scratch[1024];   // sink for lo-lane publishes

  const int  tid = (int)threadIdx.x;
  const int  wv  = tid >> 6;            // 0 = wave A (h0), 1 = wave B (h1)
  const int  m   = tid & 63;
  const int  r   = m & 31;              // row owned by this lane
  const bool hi  = (m >= 32);           // secondary-matrix half
  const int  b   = (int)blockIdx.x;

  // Per-lane full 32-float row, packed to 16 f16 pairs:
  //  A: lo = Whh0[r], hi = Wih1[r].  B: lo = Whh1[r], hi = Wout (row 0, dup).
  const float* pw = (wv == 0) ? (hi ? (Wih1 + r * 32) : (Whh0 + r * 32))
                              : (hi ? Wout : (Whh1 + r * 32));
  h2 w[16];
#pragma unroll
  for (int k = 0; k < 8; ++k) {
    float4 q = ((const float4*)pw)[k];
    w[2 * k].x     = (_Float16)q.x;
    w[2 * k].y     = (_Float16)q.y;
    w[2 * k + 1].x = (_Float16)q.z;
    w[2 * k + 1].y = (_Float16)q.w;
  }

  float xw = 0.f, binv = 0.f;
  if (wv == 0) {
    if (hi) binv = bih1[r] + bhh1[r];            // u seed: b1 (no x term)
    else  { binv = bih0[r] + bhh0[r]; xw = Wih0[r]; }
  }
  const float bo = bout[0];

  // State register: lane k (k<32) holds h[k] in f32. Hi lanes carry garbage
  // copies; pack_state/BCASTH only read lanes 0..31 (even lanes).
  float hcur = (wv == 0) ? hs[b * 32 + r] : hs[2048 + b * 32 + r];

  // Wave A publish pointers: hi lanes -> uwin row r, lo lanes -> scratch.
  float* up0 = hi ? &uwin[0][r] : &scratch[r];
  float* up1 = hi ? &uwin[1][r] : &scratch[r];

  const float* xb   = x + (size_t)b * T_LEN;
  float*       outp = out + (size_t)b * T_LEN;       // outs[b*T + t]
  float*       hf   = out + (size_t)B_SZ * T_LEN;    // h_final [2,B,H]

  float obuf = 0.f;
  float xcur = 0.f;
  if (wv == 0) xcur = xb[m];            // window 0 chunk (lanes 0..31 used)

  for (int wdx = 0; wdx <= NW; ++wdx) {
    if (wv == 0) {
      if (wdx < NW) {
        // Prefetch next window's x chunk; consumed 32 steps from now.
        float xnext = 0.f;
        if (wdx + 1 < NW) {
          int xi = 32 * (wdx + 1) + m; if (xi > T_LEN - 1) xi = T_LEN - 1;
          xnext = xb[xi];
        }
        float* up = (wdx & 1) ? up1 : up0;
#pragma unroll 4
        for (int t2 = 0; t2 < 32; ++t2) {
          float xv   = rl(xcur, t2);        // x(t)   (off-chain, early)
          float seed = fmaf(xv, xw, binv);  // lo: x*Wih0 + b0; hi: b1
          h2 hpk = pack_state(hcur);        // h0n(t-1) packed pairs
          h2 hb[16];
          BCASTH(hb, hpk);                  // 16 readlanes, clustered...
          SCHED_FENCE();                    // ...then dots (no interleave)
          float acc  = dot32h(w, hb, seed); // lo: tanh arg; hi: u(t-1)
          up[t2 * 32] = acc;                // hi publishes u; lo -> scratch
          hcur = tanh_fast(acc);            // lo lanes: h0n(t)
        }
        xcur = xnext;
      }
    } else {
      if (wdx >= 1) {
        const int wb = wdx - 1;             // steps t = 32*wb-1 .. 32*wb+30
        const float* ub = &uwin[wb & 1][r];
        float uval = ub[0];                 // u(32*wb-1); per-row broadcast
#pragma unroll 4
        for (int t2 = 0; t2 < 32; ++t2) {
          const int t = 32 * wb - 1 + t2;
          h2 hpk = pack_state(hcur);        // h1n(t-1) packed pairs
          h2 hb[16];
          BCASTH(hb, hpk);                  // 16 readlanes, clustered...
          SCHED_FENCE();                    // ...then dots (no interleave)
          float acc = dot32h(w, hb, 0.f);   // lo: Whh1 dot; hi: Wout dot
          float unext = ub[((t2 + 1) & 31) * 32];  // pipelined u-read
          float h1n = tanh_fast(uval + acc);
          obuf = (m == 32 + t2) ? acc : obuf;      // hi lane t2: out(t-1)-bo
          if (t >= 0) hcur = h1n;           // uniform guard (skips wb=0,t2=0)
          uval = unext;
        }
        const int idx = 32 * wb - 2 + r;    // hi lane 32+k holds out(32wb-2+k)
        if (hi && idx >= 0) outp[idx] = obuf + bo;   // coalesced store
      }
    }
    __syncthreads();   // window handoff (uwin parity swap)
  }

  // Epilogue 1 (wave A): publish u(T-1) from h0n(T-1); store h_final L0.
  if (wv == 0) {
    h2 hpk = pack_state(hcur);              // h0n(T-1)
    h2 hb[16];
    BCASTH(hb, hpk);
    float acc = dot32h(w, hb, binv);        // hi: b1 + Wih1 . h0n(T-1)
    if (hi) uwin[0][r] = acc;
    else    hf[b * 32 + r] = hcur;          // h_final layer 0 (full f32)
  }
  __syncthreads();

  // Epilogue 2 (wave B): h1n(T-1), out(T-2), out(T-1), h_final L1.
  if (wv == 1) {
    float uT = uwin[0][r];
    h2 hpk = pack_state(hcur);              // h1n(T-2)
    h2 hb[16];
    BCASTH(hb, hpk);
    float acc = dot32h(w, hb, 0.f);
    if (m == 32) outp[T_LEN - 2] = acc + bo;      // Wout . h1n(T-2)
    float h1T = tanh_fast(uT + acc);
    h2 hpk2 = pack_state(h1T);              // h1n(T-1)
    h2 hb2[16];
    BCASTH(hb2, hpk2);
    float acc2 = dot32h(w, hb2, 0.f);
    if (m == 32) outp[T_LEN - 1] = acc2 + bo;     // Wout . h1n(T-1)
    if (!hi) hf[2048 + b * 32 + r] = h1T;   // h_final layer 1 (full f32)
  }
}

extern "C" void kernel_launch(void* const* d_in, const int* in_sizes, int n_in,
                              void* d_out, int out_size, void* d_ws, size_t ws_size,
                              hipStream_t stream) {
  rnn2_kernel<<<dim3(B_SZ), dim3(128), 0, stream>>>(
      (const float*)d_in[0],  (const float*)d_in[1],  (const float*)d_in[2],
      (const float*)d_in[3],  (const float*)d_in[4],  (const float*)d_in[5],
      (const float*)d_in[6],  (const float*)d_in[7],  (const float*)d_in[8],
      (const float*)d_in[9],  (const float*)d_in[10], (const float*)d_in[11],
      (float*)d_out);
}

// Round 10
// 2012.963 us; speedup vs baseline: 1.6609x; 1.0502x over previous
//
#include <hip/hip_runtime.h>

// Two-layer tanh RNN, H=32, B=64, T=16384. Latency-bound sequential scan.
//
// Round-26: R18 skeleton (proven, 1952 us) with the state broadcast moved
// from v_readlane (VALU) to ds_bpermute_b32 (LDS-crossbar pipe).
// Evidence for VALU-OCCUPANCY model: R21 braid = sum not max; R22
// co-resident waves = sum not max; R25 readlane clustering = no change.
// => the broadcast ops OCCUPY the VALU (low-rate), they don't stall it.
// ds_bpermute executes on the DS pipe: VALU freed, bpermutes pipeline
// with dots under compiler lgkmcnt. Uniform address (lane 2j, byte 8j,
// compile-time const) => wave-uniform broadcast, values bit-identical to
// readlane version. All arithmetic identical to R18 => absmax must be
// exactly 0.001953125.

#define T_LEN 16384
#define B_SZ  64
#define NW    (T_LEN / 32)   // 512 windows

#if __has_builtin(__builtin_amdgcn_exp2f)
#define EXP2(x) __builtin_amdgcn_exp2f(x)
#else
#define EXP2(x) exp2f(x)
#endif

typedef _Float16 h2 __attribute__((ext_vector_type(2)));

__device__ __forceinline__ float rl(float v, int lane) {
  return __int_as_float(__builtin_amdgcn_readlane(__float_as_int(v), lane));
}

__device__ __forceinline__ h2 rl_h2(h2 v, int lane) {
  int o = __builtin_amdgcn_readlane(__builtin_bit_cast(int, v), lane);
  return __builtin_bit_cast(h2, o);
}

// Wave-uniform broadcast via the LDS crossbar: every lane pulls the pack
// register of lane (byteaddr>>2). No LDS storage touched; DS pipe op.
__device__ __forceinline__ h2 bperm_h2(int byteaddr, h2 v) {
  int o = __builtin_amdgcn_ds_bpermute(byteaddr, __builtin_bit_cast(int, v));
  return __builtin_bit_cast(h2, o);
}

// quad_perm([1,0,3,2]): each lane sees its pair-neighbor's value.
__device__ __forceinline__ float pair_swap(float v) {
  int t = __builtin_amdgcn_update_dpp(0, __float_as_int(v), 0xB1, 0xF, 0xF, true);
  return __int_as_float(t);
}

__device__ __forceinline__ float tanh_fast(float v) {
  // tanh(v) = 1 - 2/(e^{2v}+1); e^{2v} = 2^{v*2*log2(e)}. 5-dep chain.
  float e = EXP2(v * 2.885390082f);
  return fmaf(-2.f, __builtin_amdgcn_rcpf(e + 1.f), 1.f);
}

#if __has_builtin(__builtin_amdgcn_fdot2)
#define FDOT2(a, b, c) __builtin_amdgcn_fdot2((a), (b), (c), false)
#else
#define FDOT2(a, b, c) \
  fmaf((float)(a).x, (float)(b).x, fmaf((float)(a).y, (float)(b).y, (c)))
#endif

// Pack this lane's state with its pair-neighbor: even lane 2j ends up with
// (h[2j], h[2j+1]). Odd/hi lanes hold swapped/garbage pairs — never read.
__device__ __forceinline__ h2 pack_state(float hcur) {
  float hsw = pair_swap(hcur);
  h2 p;
  p.x = (_Float16)hcur;
  p.y = (_Float16)hsw;
  return p;
}

// Broadcast 16 packed pairs from even lanes 0,2,...,30 into all lanes'
// VGPRs via ds_bpermute (byte addr 8j -> lane 2j; compile-time consts).
#define BCASTB(dst, src_pk)                                  \
  _Pragma("unroll")                                          \
  for (int j_ = 0; j_ < 16; ++j_) (dst)[j_] = bperm_h2(8 * j_, (src_pk));

// 32-term dot via 16 dot2, 4 accumulators (depth 4) + 2-level tree.
__device__ __forceinline__ float dot32h(const h2* w, const h2* hb, float seed) {
  float a0 = seed, a1 = 0.f, a2 = 0.f, a3 = 0.f;
#pragma unroll
  for (int j = 0; j < 4; ++j) {
    a0 = FDOT2(w[4 * j + 0], hb[4 * j + 0], a0);
    a1 = FDOT2(w[4 * j + 1], hb[4 * j + 1], a1);
    a2 = FDOT2(w[4 * j + 2], hb[4 * j + 2], a2);
    a3 = FDOT2(w[4 * j + 3], hb[4 * j + 3], a3);
  }
  return (a0 + a1) + (a2 + a3);
}

__global__ __launch_bounds__(128, 1) void rnn2_kernel(
    const float* __restrict__ x,    const float* __restrict__ hs,
    const float* __restrict__ Wih0, const float* __restrict__ Whh0,
    const float* __restrict__ bih0, const float* __restrict__ bhh0,
    const float* __restrict__ Wih1, const float* __restrict__ Whh1,
    const float* __restrict__ bih1, const float* __restrict__ bhh1,
    const float* __restrict__ Wout, const float* __restrict__ bout,
    float* __restrict__ out)
{
  __shared__ __align__(16) float uwin[2][1024];   // A->B; slot t2*32 + row
  __shared__ __align__(16) float scratch[1024];   // sink for lo-lane publishes

  const int  tid = (int)threadIdx.x;
  const int  wv  = tid >> 6;            // 0 = wave A (h0), 1 = wave B (h1)
  const int  m   = tid & 63;
  const int  r   = m & 31;              // row owned by this lane
  const bool hi  = (m >= 32);           // secondary-matrix half
  const int  b   = (int)blockIdx.x;

  // Per-lane full 32-float row, packed to 16 f16 pairs:
  //  A: lo = Whh0[r], hi = Wih1[r].  B: lo = Whh1[r], hi = Wout (row 0, dup).
  const float* pw = (wv == 0) ? (hi ? (Wih1 + r * 32) : (Whh0 + r * 32))
                              : (hi ? Wout : (Whh1 + r * 32));
  h2 w[16];
#pragma unroll
  for (int k = 0; k < 8; ++k) {
    float4 q = ((const float4*)pw)[k];
    w[2 * k].x     = (_Float16)q.x;
    w[2 * k].y     = (_Float16)q.y;
    w[2 * k + 1].x = (_Float16)q.z;
    w[2 * k + 1].y = (_Float16)q.w;
  }

  float xw = 0.f, binv = 0.f;
  if (wv == 0) {
    if (hi) binv = bih1[r] + bhh1[r];            // u seed: b1 (no x term)
    else  { binv = bih0[r] + bhh0[r]; xw = Wih0[r]; }
  }
  const float bo = bout[0];

  // State register: lane k (k<32) holds h[k] in f32. Hi lanes carry garbage
  // copies; pack_state/BCASTB only read lanes 0..31 (even lanes).
  float hcur = (wv == 0) ? hs[b * 32 + r] : hs[2048 + b * 32 + r];

  // Wave A publish pointers: hi lanes -> uwin row r, lo lanes -> scratch.
  float* up0 = hi ? &uwin[0][r] : &scratch[r];
  float* up1 = hi ? &uwin[1][r] : &scratch[r];

  const float* xb   = x + (size_t)b * T_LEN;
  float*       outp = out + (size_t)b * T_LEN;       // outs[b*T + t]
  float*       hf   = out + (size_t)B_SZ * T_LEN;    // h_final [2,B,H]

  float obuf = 0.f;
  float xcur = 0.f;
  if (wv == 0) xcur = xb[m];            // window 0 chunk (lanes 0..31 used)

  for (int wdx = 0; wdx <= NW; ++wdx) {
    if (wv == 0) {
      if (wdx < NW) {
        // Prefetch next window's x chunk; consumed 32 steps from now.
        float xnext = 0.f;
        if (wdx + 1 < NW) {
          int xi = 32 * (wdx + 1) + m; if (xi > T_LEN - 1) xi = T_LEN - 1;
          xnext = xb[xi];
        }
        float* up = (wdx & 1) ? up1 : up0;
#pragma unroll 4
        for (int t2 = 0; t2 < 32; ++t2) {
          h2 hpk = pack_state(hcur);        // h0n(t-1) packed pairs
          h2 hb[16];
          BCASTB(hb, hpk);                  // broadcast on DS pipe
          float xv   = rl(xcur, t2);        // x(t)   (off-chain)
          float seed = fmaf(xv, xw, binv);  // lo: x*Wih0 + b0; hi: b1
          float acc  = dot32h(w, hb, seed); // lo: tanh arg; hi: u(t-1)
          up[t2 * 32] = acc;                // hi publishes u; lo -> scratch
          hcur = tanh_fast(acc);            // lo lanes: h0n(t)
        }
        xcur = xnext;
      }
    } else {
      if (wdx >= 1) {
        const int wb = wdx - 1;             // steps t = 32*wb-1 .. 32*wb+30
        const float* ub = &uwin[wb & 1][r];
        float uval = ub[0];                 // u(32*wb-1); per-row broadcast
#pragma unroll 4
        for (int t2 = 0; t2 < 32; ++t2) {
          const int t = 32 * wb - 1 + t2;
          h2 hpk = pack_state(hcur);        // h1n(t-1) packed pairs
          h2 hb[16];
          BCASTB(hb, hpk);                  // broadcast on DS pipe
          float acc = dot32h(w, hb, 0.f);   // lo: Whh1 dot; hi: Wout dot
          float unext = ub[((t2 + 1) & 31) * 32];  // pipelined u-read
          float h1n = tanh_fast(uval + acc);
          obuf = (m == 32 + t2) ? acc : obuf;      // hi lane t2: out(t-1)-bo
          if (t >= 0) hcur = h1n;           // uniform guard (skips wb=0,t2=0)
          uval = unext;
        }
        const int idx = 32 * wb - 2 + r;    // hi lane 32+k holds out(32wb-2+k)
        if (hi && idx >= 0) outp[idx] = obuf + bo;   // coalesced store
      }
    }
    __syncthreads();   // window handoff (uwin parity swap)
  }

  // Epilogue 1 (wave A): publish u(T-1) from h0n(T-1); store h_final L0.
  if (wv == 0) {
    h2 hpk = pack_state(hcur);              // h0n(T-1)
    h2 hb[16];
    BCASTB(hb, hpk);
    float acc = dot32h(w, hb, binv);        // hi: b1 + Wih1 . h0n(T-1)
    if (hi) uwin[0][r] = acc;
    else    hf[b * 32 + r] = hcur;          // h_final layer 0 (full f32)
  }
  __syncthreads();

  // Epilogue 2 (wave B): h1n(T-1), out(T-2), out(T-1), h_final L1.
  if (wv == 1) {
    float uT = uwin[0][r];
    h2 hpk = pack_state(hcur);              // h1n(T-2)
    h2 hb[16];
    BCASTB(hb, hpk);
    float acc = dot32h(w, hb, 0.f);
    if (m == 32) outp[T_LEN - 2] = acc + bo;      // Wout . h1n(T-2)
    float h1T = tanh_fast(uT + acc);
    h2 hpk2 = pack_state(h1T);              // h1n(T-1)
    h2 hb2[16];
    BCASTB(hb2, hpk2);
    float acc2 = dot32h(w, hb2, 0.f);
    if (m == 32) outp[T_LEN - 1] = acc2 + bo;     // Wout . h1n(T-1)
    if (!hi) hf[2048 + b * 32 + r] = h1T;   // h_final layer 1 (full f32)
  }
}

extern "C" void kernel_launch(void* const* d_in, const int* in_sizes, int n_in,
                              void* d_out, int out_size, void* d_ws, size_t ws_size,
                              hipStream_t stream) {
  rnn2_kernel<<<dim3(B_SZ), dim3(128), 0, stream>>>(
      (const float*)d_in[0],  (const float*)d_in[1],  (const float*)d_in[2],
      (const float*)d_in[3],  (const float*)d_in[4],  (const float*)d_in[5],
      (const float*)d_in[6],  (const float*)d_in[7],  (const float*)d_in[8],
      (const float*)d_in[9],  (const float*)d_in[10], (const float*)d_in[11],
      (float*)d_out);
}

// Round 11
// 1838.336 us; speedup vs baseline: 1.8187x; 1.0950x over previous
//
#include <hip/hip_runtime.h>

// Two-layer tanh RNN, H=32, B=64, T=16384. Latency-bound sequential scan.
//
// Round-27: R26 skeleton (bpermute broadcast, 1950 us green) + chain/issue
// micro-cuts. Model (fits R17/R18/R22/R25/R26): step = instrs x ~2.3 cyc
// + ~180 cyc un-overlappable chain (tanh 64, pack 12, bcast tail 47,
// dot tail 25, hazards). Cuts:
//  (1) 2*log2(e) folded into f16 weights+seeds at init (wave A both
//      halves -> published u arrives pre-scaled; wave B lo half only,
//      Wout raw). Removes the v_mul at tanh's chain head on both waves.
//  (2) wave B uval folded into the dot seed (off-chain cndmask replaces
//      on-chain v_add).
//  (3) pack via DPP pair-swap (f32) + ONE v_cvt_pkrtz_f16_f32 (-1 instr;
//      RTZ rounding, negligible vs 1.32e-2 threshold).
//  (4) unroll 8 (loop overhead halved).
// Numerics: weight quantization now of pre-scaled values + RTZ pack ->
// absmax shifts (~0.002-0.004 expected), well under threshold.

#define T_LEN 16384
#define B_SZ  64
#define NW    (T_LEN / 32)   // 512 windows
#define TSC   2.885390082f   // 2*log2(e)

#if __has_builtin(__builtin_amdgcn_exp2f)
#define EXP2(x) __builtin_amdgcn_exp2f(x)
#else
#define EXP2(x) exp2f(x)
#endif

typedef _Float16 h2 __attribute__((ext_vector_type(2)));

__device__ __forceinline__ float rl(float v, int lane) {
  return __int_as_float(__builtin_amdgcn_readlane(__float_as_int(v), lane));
}

// Wave-uniform broadcast via the LDS crossbar: every lane pulls the pack
// register of lane (byteaddr>>2). No LDS storage touched; DS pipe op.
__device__ __forceinline__ h2 bperm_h2(int byteaddr, h2 v) {
  int o = __builtin_amdgcn_ds_bpermute(byteaddr, __builtin_bit_cast(int, v));
  return __builtin_bit_cast(h2, o);
}

// quad_perm([1,0,3,2]): each lane sees its pair-neighbor's value.
__device__ __forceinline__ float pair_swap(float v) {
  int t = __builtin_amdgcn_update_dpp(0, __float_as_int(v), 0xB1, 0xF, 0xF, true);
  return __int_as_float(t);
}

// tanh with the 2*log2(e) scale PRE-FOLDED into the argument:
// tanh = 1 - 2/(2^v + 1), v = 2*log2(e)*x. 4-dep chain (mul removed).
__device__ __forceinline__ float tanh_pre(float v) {
  float e = EXP2(v);
  return fmaf(-2.f, __builtin_amdgcn_rcpf(e + 1.f), 1.f);
}

#if __has_builtin(__builtin_amdgcn_fdot2)
#define FDOT2(a, b, c) __builtin_amdgcn_fdot2((a), (b), (c), false)
#else
#define FDOT2(a, b, c) \
  fmaf((float)(a).x, (float)(b).x, fmaf((float)(a).y, (float)(b).y, (c)))
#endif

// Pack this lane's state with its pair-neighbor: even lane 2j ends with
// (h[2j], h[2j+1]). DPP on f32 first, then ONE packed convert (RTZ).
__device__ __forceinline__ h2 pack_state(float hcur) {
  float hsw = pair_swap(hcur);
#if __has_builtin(__builtin_amdgcn_cvt_pkrtz)
  return __builtin_bit_cast(h2, __builtin_amdgcn_cvt_pkrtz(hcur, hsw));
#else
  h2 p; p.x = (_Float16)hcur; p.y = (_Float16)hsw; return p;
#endif
}

// Broadcast 16 packed pairs from even lanes 0,2,...,30 into all lanes'
// VGPRs via ds_bpermute (byte addr 8j -> lane 2j; compile-time consts).
#define BCASTB(dst, src_pk)                                  \
  _Pragma("unroll")                                          \
  for (int j_ = 0; j_ < 16; ++j_) (dst)[j_] = bperm_h2(8 * j_, (src_pk));

// 32-term dot via 16 dot2, 4 accumulators (depth 4) + 2-level tree.
__device__ __forceinline__ float dot32h(const h2* w, const h2* hb, float seed) {
  float a0 = seed, a1 = 0.f, a2 = 0.f, a3 = 0.f;
#pragma unroll
  for (int j = 0; j < 4; ++j) {
    a0 = FDOT2(w[4 * j + 0], hb[4 * j + 0], a0);
    a1 = FDOT2(w[4 * j + 1], hb[4 * j + 1], a1);
    a2 = FDOT2(w[4 * j + 2], hb[4 * j + 2], a2);
    a3 = FDOT2(w[4 * j + 3], hb[4 * j + 3], a3);
  }
  return (a0 + a1) + (a2 + a3);
}

__global__ __launch_bounds__(128, 1) void rnn2_kernel(
    const float* __restrict__ x,    const float* __restrict__ hs,
    const float* __restrict__ Wih0, const float* __restrict__ Whh0,
    const float* __restrict__ bih0, const float* __restrict__ bhh0,
    const float* __restrict__ Wih1, const float* __restrict__ Whh1,
    const float* __restrict__ bih1, const float* __restrict__ bhh1,
    const float* __restrict__ Wout, const float* __restrict__ bout,
    float* __restrict__ out)
{
  __shared__ __align__(16) float uwin[2][1024];   // A->B; slot t2*32 + row
  __shared__ __align__(16) float scratch[1024];   // sink for lo-lane publishes

  const int  tid = (int)threadIdx.x;
  const int  wv  = tid >> 6;            // 0 = wave A (h0), 1 = wave B (h1)
  const int  m   = tid & 63;
  const int  r   = m & 31;              // row owned by this lane
  const bool hi  = (m >= 32);           // secondary-matrix half
  const int  b   = (int)blockIdx.x;

  // Per-lane full 32-float row, packed to 16 f16 pairs, with the tanh
  // input scale TSC pre-folded where the dot feeds tanh (or the published
  // u, which wave B consumes as a pre-scaled tanh seed):
  //  A: lo = TSC*Whh0[r], hi = TSC*Wih1[r]   (published u = TSC*u_raw)
  //  B: lo = TSC*Whh1[r], hi = Wout (raw; feeds out, not tanh)
  const float* pw = (wv == 0) ? (hi ? (Wih1 + r * 32) : (Whh0 + r * 32))
                              : (hi ? Wout : (Whh1 + r * 32));
  const float wsc = (wv == 0) ? TSC : (hi ? 1.f : TSC);
  h2 w[16];
#pragma unroll
  for (int k = 0; k < 8; ++k) {
    float4 q = ((const float4*)pw)[k];
    w[2 * k].x     = (_Float16)(q.x * wsc);
    w[2 * k].y     = (_Float16)(q.y * wsc);
    w[2 * k + 1].x = (_Float16)(q.z * wsc);
    w[2 * k + 1].y = (_Float16)(q.w * wsc);
  }

  float xw = 0.f, binv = 0.f;
  if (wv == 0) {
    if (hi) binv = TSC * (bih1[r] + bhh1[r]);    // u seed: TSC*b1
    else  { binv = TSC * (bih0[r] + bhh0[r]); xw = TSC * Wih0[r]; }
  }
  const float bo = bout[0];

  // State register: lane k (k<32) holds h[k] in f32 (raw, unscaled). Hi
  // lanes carry garbage copies; pack_state/BCASTB read even lanes 0..30.
  float hcur = (wv == 0) ? hs[b * 32 + r] : hs[2048 + b * 32 + r];

  // Wave A publish pointers: hi lanes -> uwin row r, lo lanes -> scratch.
  float* up0 = hi ? &uwin[0][r] : &scratch[r];
  float* up1 = hi ? &uwin[1][r] : &scratch[r];

  const float* xb   = x + (size_t)b * T_LEN;
  float*       outp = out + (size_t)b * T_LEN;       // outs[b*T + t]
  float*       hf   = out + (size_t)B_SZ * T_LEN;    // h_final [2,B,H]

  float obuf = 0.f;
  float xcur = 0.f;
  if (wv == 0) xcur = xb[m];            // window 0 chunk (lanes 0..31 used)

  for (int wdx = 0; wdx <= NW; ++wdx) {
    if (wv == 0) {
      if (wdx < NW) {
        // Prefetch next window's x chunk; consumed 32 steps from now.
        float xnext = 0.f;
        if (wdx + 1 < NW) {
          int xi = 32 * (wdx + 1) + m; if (xi > T_LEN - 1) xi = T_LEN - 1;
          xnext = xb[xi];
        }
        float* up = (wdx & 1) ? up1 : up0;
#pragma unroll 8
        for (int t2 = 0; t2 < 32; ++t2) {
          h2 hpk = pack_state(hcur);        // h0n(t-1) packed pairs
          h2 hb[16];
          BCASTB(hb, hpk);                  // broadcast on DS pipe
          float xv   = rl(xcur, t2);        // x(t)   (off-chain)
          float seed = fmaf(xv, xw, binv);  // lo: TSC*(x*W+b0); hi: TSC*b1
          float acc  = dot32h(w, hb, seed); // lo: tanh arg; hi: TSC*u(t-1)
          up[t2 * 32] = acc;                // hi publishes u; lo -> scratch
          hcur = tanh_pre(acc);             // lo lanes: h0n(t)
        }
        xcur = xnext;
      }
    } else {
      if (wdx >= 1) {
        const int wb = wdx - 1;             // steps t = 32*wb-1 .. 32*wb+30
        const float* ub = &uwin[wb & 1][r];
        float uval = ub[0];                 // TSC*u(32*wb-1)
#pragma unroll 8
        for (int t2 = 0; t2 < 32; ++t2) {
          const int t = 32 * wb - 1 + t2;
          h2 hpk = pack_state(hcur);        // h1n(t-1) packed pairs
          h2 hb[16];
          BCASTB(hb, hpk);                  // broadcast on DS pipe
          float sB  = hi ? 0.f : uval;      // uval folded into seed
          float acc = dot32h(w, hb, sB);    // lo: tanh arg; hi: out(t-1)-bo
          float unext = ub[((t2 + 1) & 31) * 32];  // pipelined u-read
          float h1n = tanh_pre(acc);
          obuf = (m == 32 + t2) ? acc : obuf;      // hi lane t2: out(t-1)-bo
          if (t >= 0) hcur = h1n;           // uniform guard (skips wb=0,t2=0)
          uval = unext;
        }
        const int idx = 32 * wb - 2 + r;    // hi lane 32+k holds out(32wb-2+k)
        if (hi && idx >= 0) outp[idx] = obuf + bo;   // coalesced store
      }
    }
    __syncthreads();   // window handoff (uwin parity swap)
  }

  // Epilogue 1 (wave A): publish TSC*u(T-1) from h0n(T-1); h_final L0.
  if (wv == 0) {
    h2 hpk = pack_state(hcur);              // h0n(T-1)
    h2 hb[16];
    BCASTB(hb, hpk);
    float acc = dot32h(w, hb, binv);        // hi: TSC*(b1 + Wih1.h0n(T-1))
    if (hi) uwin[0][r] = acc;
    else    hf[b * 32 + r] = hcur;          // h_final layer 0 (full f32)
  }
  __syncthreads();

  // Epilogue 2 (wave B): h1n(T-1), out(T-2), out(T-1), h_final L1.
  if (wv == 1) {
    float uT = uwin[0][r];                  // TSC*u(T-1)
    h2 hpk = pack_state(hcur);              // h1n(T-2)
    h2 hb[16];
    BCASTB(hb, hpk);
    float acc = dot32h(w, hb, hi ? 0.f : uT);
    if (m == 32) outp[T_LEN - 2] = acc + bo;      // Wout . h1n(T-2) (raw hi)
    float h1T = tanh_pre(acc);              // valid in lo lanes
    h2 hpk2 = pack_state(h1T);              // h1n(T-1)
    h2 hb2[16];
    BCASTB(hb2, hpk2);
    float acc2 = dot32h(w, hb2, 0.f);
    if (m == 32) outp[T_LEN - 1] = acc2 + bo;     // Wout . h1n(T-1)
    if (!hi) hf[2048 + b * 32 + r] = h1T;   // h_final layer 1 (full f32)
  }
}

extern "C" void kernel_launch(void* const* d_in, const int* in_sizes, int n_in,
                              void* d_out, int out_size, void* d_ws, size_t ws_size,
                              hipStream_t stream) {
  rnn2_kernel<<<dim3(B_SZ), dim3(128), 0, stream>>>(
      (const float*)d_in[0],  (const float*)d_in[1],  (const float*)d_in[2],
      (const float*)d_in[3],  (const float*)d_in[4],  (const float*)d_in[5],
      (const float*)d_in[6],  (const float*)d_in[7],  (const float*)d_in[8],
      (const float*)d_in[9],  (const float*)d_in[10], (const float*)d_in[11],
      (float*)d_out);
}